// Round 5
// baseline (268.955 us; speedup 1.0000x reference)
//
#include <hip/hip_runtime.h>
#include <math.h>
#include <stdint.h>

// Problem constants (fixed by setup_inputs)
#define BATCH 8
#define CH    256
#define H     128
#define W     128
#define PLANE (H * W)            // 16384
#define NPIX  (BATCH * PLANE)    // 131072
#define NSHIFT 12                // symmetric half of the 24 shifts
#define NMAPS  13                // 12 shifted dots + normsq
#define NCHUNK 8                 // channel chunks
#define CPC    (CH / NCHUNK)     // 32 channels per chunk
#define NSTAGE (CPC / 2)         // 16 stages of 2 channels
#define SLICE  (NMAPS * NPIX)    // floats per chunk slice
#define TROWS  8                 // output rows per block
#define NTILE  (H / TROWS)       // 16
#define NCORRB (BATCH * NTILE * NCHUNK)   // 1024 corr blocks (4/CU)
#define NSTATB (BATCH)                    // 8 stats blocks

// 12 "positive" shifts: dy>0 or (dy==0 && dx>0). Negatives recovered by symmetry.
static __device__ __constant__ int S_DY[NSHIFT] = {0,0,1,1,1,1,1,2,2,2,2,2};
static __device__ __constant__ int S_DX[NSHIFT] = {1,2,-2,-1,0,1,2,-2,-1,0,1,2};

typedef unsigned int u32;

// Async global->LDS DMA, 16B per lane. Pass per-lane pointers consistent with
// uniform-base + lane*16 (HW scatters lane*size from the wave-uniform base).
__device__ __forceinline__ void dma16(const float* g, void* l) {
    const __attribute__((address_space(1))) u32* gp =
        (const __attribute__((address_space(1))) u32*)g;
    __attribute__((address_space(3))) u32* lp =
        (__attribute__((address_space(3))) u32*)(u32)(uintptr_t)l;
    __builtin_amdgcn_global_load_lds(gp, lp, 16, 0, 0);
}

// ---------------------------------------------------------------------------
// Kernel C: fused correlation + per-image stats (+ out zero).
// Corr blocks [0, NCORRB): decode chunk(8) | tile(16) | b(8).
//   LDS layout: [2 ch][10 rows][32 x-quads] float4 (quad = 4 consecutive x of
//   one channel plane) — contiguous in global, staged via global_load_lds.
//   256 thr = 32 quads x 8 output rows; each thread: 4 px x 13 maps (52 accs),
//   both stage channels. Edge quads read wrap garbage — provably unconsumed.
// Stats blocks [NCORRB, NCORRB+NSTATB): one block per image, direct writes.
// ---------------------------------------------------------------------------
__global__ __launch_bounds__(256, 4) void k_corr(const float* __restrict__ er,
                                                 const int* __restrict__ seg,
                                                 const int* __restrict__ gtb,
                                                 float* __restrict__ slices,
                                                 int* __restrict__ cnt,
                                                 int* __restrict__ inc,
                                                 float* __restrict__ out) {
    __shared__ float4 lds4[648];     // 2*10*32 = 640 + slack for q+1 overrun
    int t = threadIdx.x;

    if (blockIdx.x >= NCORRB) {
        // ---- stats path: one block per image, full-plane scan ----
        int b = blockIdx.x - NCORRB;
        int my_cnt = 0, my_any = 0;
        for (int i = t; i < PLANE; i += 256) {
            int s = seg[b * PLANE + i];
            int g = gtb[b * PLANE + i];
            int s0 = (s == 255) ? 0 : s;
            int g0 = (g == 255) ? 0 : g;
            if (s0 > 0 && g0 > 0) {
                my_any = 1;
                int y = i >> 7, x = i & 127;
                if (y >= 2 && y < H - 2 && x >= 2 && x < W - 2) my_cnt++;
            }
        }
        for (int o = 32; o > 0; o >>= 1) {
            my_cnt += __shfl_down(my_cnt, o, 64);
            my_any |= __shfl_down(my_any, o, 64);
        }
        __shared__ int sc[4], sa[4];
        int lane = t & 63, wid = t >> 6;
        if (lane == 0) { sc[wid] = my_cnt; sa[wid] = my_any; }
        __syncthreads();
        if (t == 0) {
            cnt[b] = sc[0] + sc[1] + sc[2] + sc[3];
            inc[b] = sa[0] | sa[1] | sa[2] | sa[3];
            if (b == 0) out[0] = 0.0f;
        }
        return;
    }

    // ---- correlation path ----
    int blk = blockIdx.x;
    int chunk = blk & 7;
    int tile  = (blk >> 3) & 15;
    int b     = blk >> 7;
    int y0 = tile * TROWS;
    int c0 = chunk * CPC;
    int q = t & 31;                  // x-quad: pixels 4q..4q+3
    int r = (t >> 5) & 7;            // output row y0+r
    int w = t >> 6;                  // wave id
    int ln = t & 63;                 // lane id

    float accN[4], acc01[4], acc02[4], acc1[5][4], acc2[5][4];
#pragma unroll
    for (int j = 0; j < 4; ++j) {
        accN[j] = 0.f; acc01[j] = 0.f; acc02[j] = 0.f;
#pragma unroll
        for (int d = 0; d < 5; ++d) { acc1[d][j] = 0.f; acc2[d][j] = 0.f; }
    }

    const float* base = er + (size_t)b * CH * PLANE;

    for (int s = 0; s < NSTAGE; ++s) {
        __syncthreads();             // previous stage's LDS reads done
        // stage 2 channels x 10 rows via DMA: instr i = (ch, row-pair rp),
        // each covers 2 rows = 1 KB (64 lanes x 16B). Distributed over waves.
        const float* cb = base + (size_t)(c0 + 2 * s) * PLANE;
#pragma unroll
        for (int i = 0; i < 10; ++i) {
            if ((i & 3) == w) {
                int ch = i / 5, rp = i % 5;
                int y = y0 + 2 * rp;
                if (y < H) {
                    const float* g = cb + (size_t)ch * PLANE + y * W + ln * 4;
                    char* l = (char*)(lds4 + (ch * 10 + 2 * rp) * 32) + ln * 16;
                    dma16(g, l);
                }
            }
        }
        __syncthreads();             // drains vmcnt(0): staged data visible

#pragma unroll
        for (int ch = 0; ch < 2; ++ch) {
            const float4* Lrow = lds4 + (ch * 10 + r) * 32;      // center row
            const float4* Mrow = Lrow + 32;                      // row +1
            const float4* Nrow = Lrow + 64;                      // row +2
            float4 A = Lrow[q], B = Lrow[q + 1];
            float4 C4 = Mrow[q - 1], D4 = Mrow[q], E4 = Mrow[q + 1];
            float4 F4 = Nrow[q - 1], G4 = Nrow[q], H4 = Nrow[q + 1];
            float w8_[8] = {A.x, A.y, A.z, A.w, B.x, B.y, B.z, B.w};
            float v_[12] = {C4.x, C4.y, C4.z, C4.w, D4.x, D4.y, D4.z, D4.w,
                            E4.x, E4.y, E4.z, E4.w};
            float u_[12] = {F4.x, F4.y, F4.z, F4.w, G4.x, G4.y, G4.z, G4.w,
                            H4.x, H4.y, H4.z, H4.w};
#pragma unroll
            for (int j = 0; j < 4; ++j) {
                float a = w8_[j];
                accN[j]  = fmaf(a, a,          accN[j]);
                acc01[j] = fmaf(a, w8_[j + 1], acc01[j]);
                acc02[j] = fmaf(a, w8_[j + 2], acc02[j]);
#pragma unroll
                for (int d = 0; d < 5; ++d) {     // dx = d-2
                    acc1[d][j] = fmaf(a, v_[j + d + 2], acc1[d][j]);
                    acc2[d][j] = fmaf(a, u_[j + d + 2], acc2[d][j]);
                }
            }
        }
    }

    // coalesced float4 stores into this chunk's private slice
    float* sp = slices + (size_t)chunk * SLICE;
    int pix = b * PLANE + (y0 + r) * W + 4 * q;
    *(float4*)(sp + 0 * NPIX + pix) = make_float4(acc01[0], acc01[1], acc01[2], acc01[3]);
    *(float4*)(sp + 1 * NPIX + pix) = make_float4(acc02[0], acc02[1], acc02[2], acc02[3]);
#pragma unroll
    for (int d = 0; d < 5; ++d) {
        *(float4*)(sp + (2 + d) * NPIX + pix) =
            make_float4(acc1[d][0], acc1[d][1], acc1[d][2], acc1[d][3]);
        *(float4*)(sp + (7 + d) * NPIX + pix) =
            make_float4(acc2[d][0], acc2[d][1], acc2[d][2], acc2[d][3]);
    }
    *(float4*)(sp + 12 * NPIX + pix) = make_float4(accN[0], accN[1], accN[2], accN[3]);
}

// ---------------------------------------------------------------------------
// Kernel R: reduce the 8 chunk slices into the combined maps (float4 wide)
// ---------------------------------------------------------------------------
__global__ __launch_bounds__(256) void k_combine(const float4* __restrict__ sl,
                                                 float4* __restrict__ comb) {
    int i = blockIdx.x * 256 + threadIdx.x;     // over SLICE/4 elements (exact)
    float4 s = sl[i];
#pragma unroll
    for (int c = 1; c < NCHUNK; ++c) {
        float4 v = sl[(size_t)c * (SLICE / 4) + i];
        s.x += v.x; s.y += v.y; s.z += v.z; s.w += v.w;
    }
    comb[i] = s;
}

// ---------------------------------------------------------------------------
// Kernel L: per-valid-pixel loss assembly (factor computed inline) + reduce
// comb layout: maps 0..11 = shifted dots (S order), map 12 = normsq
// ---------------------------------------------------------------------------
__global__ __launch_bounds__(256) void k_loss(const float* __restrict__ comb,
                                              const int* __restrict__ seg,
                                              const int* __restrict__ gtb,
                                              const int* __restrict__ cnt,
                                              const int* __restrict__ inc,
                                              float* __restrict__ out) {
    const float* dots   = comb;
    const float* normsq = comb + NSHIFT * NPIX;
    int idx = blockIdx.x * 256 + threadIdx.x;
    int b = idx >> 14;
    int rem = idx & (PLANE - 1);
    int y = rem >> 7;
    int x = rem & 127;

    // factor = inc_b ? 1/(24 * max(cnt_b,1) * scale_num) : 0  (uniform per block)
    int sn = 0;
#pragma unroll
    for (int b2 = 0; b2 < BATCH; b2++) sn += (inc[b2] != 0);
    if (sn < 1) sn = 1;
    int cb = cnt[b]; if (cb < 1) cb = 1;
    float factor = inc[b] ? 1.0f / (24.0f * (float)cb * (float)sn) : 0.0f;

    float val = 0.0f;
    if (y >= 2 && y < H - 2 && x >= 2 && x < W - 2) {
        int sp = seg[idx];
        int gp = gtb[idx];
        int s0 = (sp == 255) ? 0 : sp;
        int g0 = (gp == 255) ? 0 : gp;
        if (s0 > 0 && g0 > 0) {
            float np = fmaxf(sqrtf(normsq[idx]), 1e-8f);
            float sum = 0.0f;
#pragma unroll
            for (int i = 0; i < NSHIFT; ++i) {
                int off = S_DY[i] * W + S_DX[i];
                // + shift: cos(p, p+d)
                {
                    float d  = dots[i * NPIX + idx];
                    float nn = fmaxf(sqrtf(normsq[idx + off]), 1e-8f);
                    float cosv = d / (np * nn);
                    int sq = seg[idx + off];
                    float lab = (sp == sq && sp < 2) ? 1.0f : 0.0f;
                    float tt = cosv - lab;
                    sum = fmaf(tt, tt, sum);
                }
                // - shift: cos(p, p-d) = dot_d(p-d)/(norm(p)norm(p-d))
                {
                    float d  = dots[i * NPIX + idx - off];
                    float nn = fmaxf(sqrtf(normsq[idx - off]), 1e-8f);
                    float cosv = d / (np * nn);
                    int sq = seg[idx - off];
                    float lab = (sp == sq && sp < 2) ? 1.0f : 0.0f;
                    float tt = cosv - lab;
                    sum = fmaf(tt, tt, sum);
                }
            }
            val = sum * factor;
        }
    }

    // block reduction: wave shuffle then LDS across 4 waves
    for (int o = 32; o > 0; o >>= 1)
        val += __shfl_down(val, o, 64);
    __shared__ float wsum[4];
    int lane = threadIdx.x & 63;
    int wid  = threadIdx.x >> 6;
    if (lane == 0) wsum[wid] = val;
    __syncthreads();
    if (threadIdx.x == 0) {
        float s = wsum[0] + wsum[1] + wsum[2] + wsum[3];
        atomicAdd(out, s);
    }
}

// ---------------------------------------------------------------------------
extern "C" void kernel_launch(void* const* d_in, const int* in_sizes, int n_in,
                              void* d_out, int out_size, void* d_ws, size_t ws_size,
                              hipStream_t stream) {
    const float* er  = (const float*)d_in[0];
    const int*   seg = (const int*)d_in[1];
    const int*   gtb = (const int*)d_in[2];
    float* out = (float*)d_out;

    float* ws     = (float*)d_ws;
    float* comb   = ws;                          // 13 * NPIX floats (6.8 MB)
    float* slices = comb + SLICE;                // 8 * 13 * NPIX floats (54.5 MB)
    int*   cnt    = (int*)(slices + (size_t)NCHUNK * SLICE);   // 8 ints
    int*   inc    = cnt + 8;                     // 8 ints

    hipLaunchKernelGGL(k_corr,    dim3(NCORRB + NSTATB), dim3(256), 0, stream,
                       er, seg, gtb, slices, cnt, inc, out);
    hipLaunchKernelGGL(k_combine, dim3(SLICE / 4 / 256), dim3(256), 0, stream,
                       (const float4*)slices, (float4*)comb);
    hipLaunchKernelGGL(k_loss,    dim3(NPIX / 256), dim3(256), 0, stream,
                       comb, seg, gtb, cnt, inc, out);
}

// Round 6
// 221.283 us; speedup vs baseline: 1.2154x; 1.2154x over previous
//
#include <hip/hip_runtime.h>
#include <math.h>

// Problem constants (fixed by setup_inputs)
#define BATCH 8
#define CH    256
#define H     128
#define W     128
#define PLANE (H * W)            // 16384
#define NPIX  (BATCH * PLANE)    // 131072
#define NSHIFT 12                // symmetric half of the 24 shifts
#define NMAPS  13                // 12 shifted dots + normsq
#define NCHUNK 4                 // channel chunks
#define CPC    (CH / NCHUNK)     // 64 channels per chunk
#define NZ4    (NMAPS * NPIX / 4)  // float4s to zero in comb (425984)

// 12 "positive" shifts: dy>0 or (dy==0 && dx>0). Negatives recovered by symmetry.
static __device__ __constant__ int S_DY[NSHIFT] = {0,0,1,1,1,1,1,2,2,2,2,2};
static __device__ __constant__ int S_DX[NSHIFT] = {1,2,-2,-1,0,1,2,-2,-1,0,1,2};

#define NCORRB (BATCH * 32 * NCHUNK)             // 1024 corr blocks (4/CU)
#define NSTATB (BATCH * 64)                      // 512 stats blocks

__device__ __forceinline__ void fma4(float& acc, const float4& a, const float4& b) {
    acc = fmaf(a.x, b.x, acc);
    acc = fmaf(a.y, b.y, acc);
    acc = fmaf(a.z, b.z, acc);
    acc = fmaf(a.w, b.w, acc);
}

// ---------------------------------------------------------------------------
// Kernel P: zero comb (atomic accumulator target) + cnt/inc/out
// ---------------------------------------------------------------------------
__global__ __launch_bounds__(256) void k_prep(float4* __restrict__ comb4,
                                              int* __restrict__ cnt,
                                              int* __restrict__ inc,
                                              float* __restrict__ out) {
    int i = blockIdx.x * 256 + threadIdx.x;
    if (i < NZ4) comb4[i] = make_float4(0.f, 0.f, 0.f, 0.f);
    if (blockIdx.x == 0) {
        int t = threadIdx.x;
        if (t < 8) { cnt[t] = 0; inc[t] = 0; }
        if (t == 0) out[0] = 0.0f;
    }
}

// ---------------------------------------------------------------------------
// Kernel C: fused correlation + per-image stats.
// Blocks [0, NCORRB): correlation. Grid decode: chunk(4) | tile(32) | b(8).
//   256 thr; each thread computes 2 adjacent output rows (block covers 4
//   rows, stages 6 rows x 4 channels as float4-per-pixel in LDS — this read
//   pattern measured 0 LDS bank conflicts in R3/R4).
//   Register-prefetch pipeline: next quad's 12 global loads issue during the
//   current quad's compute phase, consumed at the next ds_write.
//   atomicAdd into the combined maps (4 contenders per address).
// Blocks [NCORRB, NCORRB+NSTATB): per-image cnt/inc stats.
// __launch_bounds__(256,4): 128-VGPR budget so the 26 accumulators + 12
// prefetch regs stay in arch VGPRs (R3/R4's default bound forced 36 VGPRs ->
// AGPR shuffling tax on every FMA).
// ---------------------------------------------------------------------------
__global__ __launch_bounds__(256, 4) void k_corr(const float* __restrict__ er,
                                                 const int* __restrict__ seg,
                                                 const int* __restrict__ gtb,
                                                 float* __restrict__ comb,
                                                 int* __restrict__ cnt,
                                                 int* __restrict__ inc) {
    __shared__ float4 lds[6][132];   // 6 staged rows, x padded by 2 each side
    int t = threadIdx.x;

    if (blockIdx.x >= NCORRB) {
        // ---- stats path ----
        int blk2 = blockIdx.x - NCORRB;
        int b = blk2 >> 6;
        int i = (blk2 & 63) * 256 + t;
        int my_cnt = 0, my_any = 0;
        {
            int s = seg[b * PLANE + i];
            int g = gtb[b * PLANE + i];
            int s0 = (s == 255) ? 0 : s;
            int g0 = (g == 255) ? 0 : g;
            if (s0 > 0 && g0 > 0) {
                my_any = 1;
                int y = i >> 7, x = i & 127;
                if (y >= 2 && y < H - 2 && x >= 2 && x < W - 2) my_cnt = 1;
            }
        }
        for (int o = 32; o > 0; o >>= 1) {
            my_cnt += __shfl_down(my_cnt, o, 64);
            my_any |= __shfl_down(my_any, o, 64);
        }
        __shared__ int sc[4], sa[4];
        int lane = t & 63, wid = t >> 6;
        if (lane == 0) { sc[wid] = my_cnt; sa[wid] = my_any; }
        __syncthreads();
        if (t == 0) {
            int c = sc[0] + sc[1] + sc[2] + sc[3];
            int a = sa[0] | sa[1] | sa[2] | sa[3];
            if (c) atomicAdd(&cnt[b], c);
            if (a) atomicOr(&inc[b], 1);
        }
        return;
    }

    // ---- correlation path ----
    int blk = blockIdx.x;
    int chunk = blk & 3;
    int tile  = (blk >> 2) & 31;
    int b     = blk >> 7;
    int y0 = tile * 4;               // block covers output rows y0..y0+3
    int c0 = chunk * CPC;
    int r = t >> 7;                  // thread handles output rows y0+2r, y0+2r+1
    int x = t & 127;

    // zero the x-pad slots once (first in-loop barrier makes them visible)
    if (t < 24) {
        int row = t >> 2, col = t & 3;
        int xs = (col < 2) ? col : (col + 128);   // 0,1,130,131
        lds[row][xs] = make_float4(0.f, 0.f, 0.f, 0.f);
    }

    float accA[13], accB[13];
#pragma unroll
    for (int i = 0; i < 13; i++) { accA[i] = 0.0f; accB[i] = 0.0f; }

    const float* base = er + (size_t)b * CH * PLANE;

    // prefetch registers: 3 stage slots x 4 channels
    float pf[3][4];
    auto load_quad = [&](int c) {
#pragma unroll
        for (int k = 0; k < 3; ++k) {
            int s = t + k * 256;         // 0..767
            int row = s >> 7;            // 0..5
            int xs = s & 127;
            int y = y0 + row;
            if (y < H) {
                const float* p0 = base + (size_t)c * PLANE + y * W + xs;
                pf[k][0] = p0[0];
                pf[k][1] = p0[PLANE];
                pf[k][2] = p0[2 * PLANE];
                pf[k][3] = p0[3 * PLANE];
            } else {
                pf[k][0] = 0.f; pf[k][1] = 0.f; pf[k][2] = 0.f; pf[k][3] = 0.f;
            }
        }
    };

    load_quad(c0);
    const int iters = CPC / 4;       // 16
    for (int it = 0; it < iters; ++it) {
        __syncthreads();   // prior iter's LDS reads done
        // commit prefetched quad to LDS (vmcnt wait lands here, after overlap)
#pragma unroll
        for (int k = 0; k < 3; ++k) {
            int s = t + k * 256;
            int row = s >> 7;
            int xs = s & 127;
            lds[row][xs + 2] = make_float4(pf[k][0], pf[k][1], pf[k][2], pf[k][3]);
        }
        __syncthreads();
        if (it + 1 < iters) load_quad(c0 + 4 * (it + 1));   // overlaps compute below

        const float4* lp = &lds[2 * r][x + 2];
        float4 cA = lp[0];               // (rel row 0, dx 0)
        float4 cB = lp[132];             // (rel row 1, dx 0)
        // rel row 0: dx {0,1,2} -> accA[0..2]
        {
            float4 v1 = lp[1], v2 = lp[2];
            fma4(accA[0], cA, cA);
            fma4(accA[1], cA, v1);
            fma4(accA[2], cA, v2);
        }
        // rel row 1: dx {-2..2} -> accA[3..7]; accB[0..2] (dx 0,1,2)
        {
            float4 m2 = lp[130], m1 = lp[131], p1 = lp[133], p2 = lp[134];
            fma4(accA[3], cA, m2);
            fma4(accA[4], cA, m1);
            fma4(accA[5], cA, cB);
            fma4(accA[6], cA, p1);
            fma4(accA[7], cA, p2);
            fma4(accB[0], cB, cB);
            fma4(accB[1], cB, p1);
            fma4(accB[2], cB, p2);
        }
        // rel row 2: dx {-2..2} -> accA[8..12]; accB[3..7]
        {
            float4 m2 = lp[262], m1 = lp[263], v0 = lp[264], p1 = lp[265], p2 = lp[266];
            fma4(accA[8],  cA, m2);
            fma4(accA[9],  cA, m1);
            fma4(accA[10], cA, v0);
            fma4(accA[11], cA, p1);
            fma4(accA[12], cA, p2);
            fma4(accB[3], cB, m2);
            fma4(accB[4], cB, m1);
            fma4(accB[5], cB, v0);
            fma4(accB[6], cB, p1);
            fma4(accB[7], cB, p2);
        }
        // rel row 3: dx {-2..2} -> accB[8..12]
        {
            float4 m2 = lp[394], m1 = lp[395], v0 = lp[396], p1 = lp[397], p2 = lp[398];
            fma4(accB[8],  cB, m2);
            fma4(accB[9],  cB, m1);
            fma4(accB[10], cB, v0);
            fma4(accB[11], cB, p1);
            fma4(accB[12], cB, p2);
        }
    }

    // atomic accumulation into the combined maps (NCHUNK contenders/address)
    int pixA = b * PLANE + (y0 + 2 * r) * W + x;
    int pixB = pixA + W;
#pragma unroll
    for (int m = 0; m < NSHIFT; ++m) {
        atomicAdd(&comb[m * NPIX + pixA], accA[m + 1]);
        atomicAdd(&comb[m * NPIX + pixB], accB[m + 1]);
    }
    atomicAdd(&comb[NSHIFT * NPIX + pixA], accA[0]);
    atomicAdd(&comb[NSHIFT * NPIX + pixB], accB[0]);
}

// ---------------------------------------------------------------------------
// Kernel L: per-valid-pixel loss assembly (factor computed inline) + reduce
// comb layout: maps 0..11 = shifted dots (S order), map 12 = normsq
// ---------------------------------------------------------------------------
__global__ __launch_bounds__(256) void k_loss(const float* __restrict__ comb,
                                              const int* __restrict__ seg,
                                              const int* __restrict__ gtb,
                                              const int* __restrict__ cnt,
                                              const int* __restrict__ inc,
                                              float* __restrict__ out) {
    const float* dots   = comb;
    const float* normsq = comb + NSHIFT * NPIX;
    int idx = blockIdx.x * 256 + threadIdx.x;
    int b = idx >> 14;
    int rem = idx & (PLANE - 1);
    int y = rem >> 7;
    int x = rem & 127;

    // factor = inc_b ? 1/(24 * max(cnt_b,1) * scale_num) : 0  (uniform per block)
    int sn = 0;
#pragma unroll
    for (int b2 = 0; b2 < BATCH; b2++) sn += (inc[b2] != 0);
    if (sn < 1) sn = 1;
    int cb = cnt[b]; if (cb < 1) cb = 1;
    float factor = inc[b] ? 1.0f / (24.0f * (float)cb * (float)sn) : 0.0f;

    float val = 0.0f;
    if (y >= 2 && y < H - 2 && x >= 2 && x < W - 2) {
        int sp = seg[idx];
        int gp = gtb[idx];
        int s0 = (sp == 255) ? 0 : sp;
        int g0 = (gp == 255) ? 0 : gp;
        if (s0 > 0 && g0 > 0) {
            float np = fmaxf(sqrtf(normsq[idx]), 1e-8f);
            float sum = 0.0f;
#pragma unroll
            for (int i = 0; i < NSHIFT; ++i) {
                int off = S_DY[i] * W + S_DX[i];
                // + shift: cos(p, p+d)
                {
                    float d  = dots[i * NPIX + idx];
                    float nn = fmaxf(sqrtf(normsq[idx + off]), 1e-8f);
                    float cosv = d / (np * nn);
                    int sq = seg[idx + off];
                    float lab = (sp == sq && sp < 2) ? 1.0f : 0.0f;
                    float tt = cosv - lab;
                    sum = fmaf(tt, tt, sum);
                }
                // - shift: cos(p, p-d) = dot_d(p-d)/(norm(p)norm(p-d))
                {
                    float d  = dots[i * NPIX + idx - off];
                    float nn = fmaxf(sqrtf(normsq[idx - off]), 1e-8f);
                    float cosv = d / (np * nn);
                    int sq = seg[idx - off];
                    float lab = (sp == sq && sp < 2) ? 1.0f : 0.0f;
                    float tt = cosv - lab;
                    sum = fmaf(tt, tt, sum);
                }
            }
            val = sum * factor;
        }
    }

    // block reduction: wave shuffle then LDS across 4 waves
    for (int o = 32; o > 0; o >>= 1)
        val += __shfl_down(val, o, 64);
    __shared__ float wsum[4];
    int lane = threadIdx.x & 63;
    int wid  = threadIdx.x >> 6;
    if (lane == 0) wsum[wid] = val;
    __syncthreads();
    if (threadIdx.x == 0) {
        float s = wsum[0] + wsum[1] + wsum[2] + wsum[3];
        atomicAdd(out, s);
    }
}

// ---------------------------------------------------------------------------
extern "C" void kernel_launch(void* const* d_in, const int* in_sizes, int n_in,
                              void* d_out, int out_size, void* d_ws, size_t ws_size,
                              hipStream_t stream) {
    const float* er  = (const float*)d_in[0];
    const int*   seg = (const int*)d_in[1];
    const int*   gtb = (const int*)d_in[2];
    float* out = (float*)d_out;

    float* ws   = (float*)d_ws;
    float* comb = ws;                            // 13 * NPIX floats (6.8 MB)
    int*   cnt  = (int*)(comb + NMAPS * NPIX);   // 8 ints
    int*   inc  = cnt + 8;                       // 8 ints

    hipLaunchKernelGGL(k_prep, dim3((NZ4 + 255) / 256), dim3(256), 0, stream,
                       (float4*)comb, cnt, inc, out);
    hipLaunchKernelGGL(k_corr, dim3(NCORRB + NSTATB), dim3(256), 0, stream,
                       er, seg, gtb, comb, cnt, inc);
    hipLaunchKernelGGL(k_loss, dim3(NPIX / 256), dim3(256), 0, stream,
                       comb, seg, gtb, cnt, inc, out);
}